// Round 4
// baseline (843.052 us; speedup 1.0000x reference)
//
#include <hip/hip_runtime.h>

// ---------------------------------------------------------------------------
// ConstraintViolationLoss: build x, sparse Ax via per-XCD-replicated,
// L2-local (workgroup-scope) float atomics selected by the hardware XCC_ID,
// then violation reduction to 4 scalars:
// [penalty, mean_viol, max_viol, n_violated].
//
// Key idea: device-scope fp32 atomicAdd on gfx950 goes to the coherent
// memory-side path (round-1 profile: 16M atomics -> 500MB WRITE_SIZE).
// Workgroup-scope atomics can stay in the local per-XCD L2. Correctness
// across blocks is preserved by giving each XCD its own Ax replica, chosen
// via s_getreg(HW_REG_XCC_ID): every atomic to replica k comes only from
// XCD k and serializes at that XCD's L2. A stronger-than-requested scope
// would still be correct, just slower.
// ---------------------------------------------------------------------------

#define NREP 16   // XCC_ID measured 0..7; 16 replicas = insurance headroom

typedef int   iv4 __attribute__((ext_vector_type(4)));
typedef float fv4 __attribute__((ext_vector_type(4)));

// ------------------------------ build x ------------------------------------

__global__ void k_scatter(const float* __restrict__ src, const int* __restrict__ idx,
                          float* __restrict__ x, int n) {
    int i = blockIdx.x * blockDim.x + threadIdx.x;
    if (i < n) x[idx[i]] = src[i];
}

__global__ void k_small_int(const float* __restrict__ logits, const float* __restrict__ offs,
                            const int* __restrict__ idx, float* __restrict__ x, int n) {
    int i = blockIdx.x * blockDim.x + threadIdx.x;
    if (i >= n) return;
    const fv4* lp = reinterpret_cast<const fv4*>(logits + (size_t)i * 16);
    fv4 v0 = lp[0], v1 = lp[1], v2 = lp[2], v3 = lp[3];
    float l[16] = {v0.x, v0.y, v0.z, v0.w, v1.x, v1.y, v1.z, v1.w,
                   v2.x, v2.y, v2.z, v2.w, v3.x, v3.y, v3.z, v3.w};
    float m = l[0];
#pragma unroll
    for (int j = 1; j < 16; ++j) m = fmaxf(m, l[j]);
    float s = 0.f, ws = 0.f;
#pragma unroll
    for (int j = 0; j < 16; ++j) {
        float e = expf(l[j] - m);
        s += e;
        ws += e * (float)j;
    }
    x[idx[i]] = ws / s + offs[i];
}

__global__ void k_continuous(const int* __restrict__ vt, const float* __restrict__ vf,
                             float* __restrict__ x, int n) {
    int v = blockIdx.x * blockDim.x + threadIdx.x;
    if (v < n && vt[v] == 0) x[v] = vf[(size_t)v * 16 + 8];
}

// --------------------- edges: L2-local replicated atomics ------------------

__global__ __launch_bounds__(256) void k_edges_l2(const float* __restrict__ ef,
                                                  const int* __restrict__ rows,
                                                  const int* __restrict__ cols,
                                                  const float* __restrict__ x,
                                                  float* __restrict__ rep,
                                                  int ncon, int e4, int E) {
    int xcd;
    asm volatile("s_getreg_b32 %0, hwreg(HW_REG_XCC_ID)" : "=s"(xcd));
    float* __restrict__ r0 = rep + (size_t)(xcd & (NREP - 1)) * ncon;

    int stride = gridDim.x * blockDim.x;
    int gid = blockIdx.x * blockDim.x + threadIdx.x;
    for (int i = gid; i < e4; i += stride) {
        fv4 f = __builtin_nontemporal_load(reinterpret_cast<const fv4*>(ef) + i);
        iv4 r = __builtin_nontemporal_load(reinterpret_cast<const iv4*>(rows) + i);
        iv4 c = __builtin_nontemporal_load(reinterpret_cast<const iv4*>(cols) + i);
        __hip_atomic_fetch_add(&r0[r.x], f.x * x[c.x], __ATOMIC_RELAXED, __HIP_MEMORY_SCOPE_WORKGROUP);
        __hip_atomic_fetch_add(&r0[r.y], f.y * x[c.y], __ATOMIC_RELAXED, __HIP_MEMORY_SCOPE_WORKGROUP);
        __hip_atomic_fetch_add(&r0[r.z], f.z * x[c.z], __ATOMIC_RELAXED, __HIP_MEMORY_SCOPE_WORKGROUP);
        __hip_atomic_fetch_add(&r0[r.w], f.w * x[c.w], __ATOMIC_RELAXED, __HIP_MEMORY_SCOPE_WORKGROUP);
    }
    for (int e = (e4 << 2) + gid; e < E; e += stride) {
        __hip_atomic_fetch_add(&r0[rows[e]], ef[e] * x[cols[e]], __ATOMIC_RELAXED, __HIP_MEMORY_SCOPE_WORKGROUP);
    }
}

// fallback: direct device-scope atomics (used only if ws too small)
__global__ void k_edges(const float* __restrict__ ef, const int* __restrict__ rows,
                        const int* __restrict__ cols, const float* __restrict__ x,
                        float* __restrict__ Ax, int e4, int E) {
    int stride = gridDim.x * blockDim.x;
    int gid = blockIdx.x * blockDim.x + threadIdx.x;
    for (int i = gid; i < e4; i += stride) {
        fv4 f = reinterpret_cast<const fv4*>(ef)[i];
        iv4 r = reinterpret_cast<const iv4*>(rows)[i];
        iv4 c = reinterpret_cast<const iv4*>(cols)[i];
        atomicAdd(&Ax[r.x], f.x * x[c.x]);
        atomicAdd(&Ax[r.y], f.y * x[c.y]);
        atomicAdd(&Ax[r.z], f.z * x[c.z]);
        atomicAdd(&Ax[r.w], f.w * x[c.w]);
    }
    for (int e = e4 * 4 + gid; e < E; e += stride)
        atomicAdd(&Ax[rows[e]], ef[e] * x[cols[e]]);
}

// ------------------------------ reduction ----------------------------------

template <int R>
__global__ void k_reduce_rep(const float* __restrict__ rep, const float* __restrict__ cf,
                             float* __restrict__ acc, int ncon) {
    float lsum = 0.f, lmax = 0.f;
    unsigned lcnt = 0;
    int stride = gridDim.x * blockDim.x;
    for (int c = blockIdx.x * blockDim.x + threadIdx.x; c < ncon; c += stride) {
        float v = 0.f;
#pragma unroll
        for (int s = 0; s < R; ++s) v += rep[(size_t)s * ncon + c];
        v -= cf[(size_t)c * 8 + 1];
        v = v > 0.f ? v : 0.f;
        lsum += v;
        lmax = fmaxf(lmax, v);
        lcnt += (v > 1e-6f) ? 1u : 0u;
    }
#pragma unroll
    for (int o = 32; o > 0; o >>= 1) {
        lsum += __shfl_down(lsum, o);
        lmax = fmaxf(lmax, __shfl_down(lmax, o));
        lcnt += __shfl_down(lcnt, o);
    }
    __shared__ float ssum[4];
    __shared__ float smax[4];
    __shared__ unsigned scnt[4];
    int lane = threadIdx.x & 63, wid = threadIdx.x >> 6;
    if (lane == 0) { ssum[wid] = lsum; smax[wid] = lmax; scnt[wid] = lcnt; }
    __syncthreads();
    if (threadIdx.x == 0) {
        float bs = 0.f, bm = 0.f;
        unsigned bc = 0;
        int nw = (blockDim.x + 63) >> 6;
        for (int w = 0; w < nw; ++w) { bs += ssum[w]; bm = fmaxf(bm, smax[w]); bc += scnt[w]; }
        atomicAdd(&acc[0], bs);
        atomicMax(reinterpret_cast<unsigned*>(acc) + 1, __float_as_uint(bm));
        atomicAdd(reinterpret_cast<unsigned*>(acc) + 2, bc);
    }
}

__global__ void k_final(const float* __restrict__ acc, float* __restrict__ out, int ncon) {
    if (blockIdx.x == 0 && threadIdx.x == 0) {
        float sum = acc[0];
        float mx = __uint_as_float(reinterpret_cast<const unsigned*>(acc)[1]);
        unsigned cnt = reinterpret_cast<const unsigned*>(acc)[2];
        float mean = sum / (float)ncon;
        out[0] = mean + 0.1f * mx;
        out[1] = mean;
        out[2] = mx;
        out[3] = (float)cnt;
    }
}

// ------------------------------ launcher -----------------------------------

extern "C" void kernel_launch(void* const* d_in, const int* in_sizes, int n_in,
                              void* d_out, int out_size, void* d_ws, size_t ws_size,
                              hipStream_t stream) {
    const float* prob_bin     = (const float*)d_in[0];
    const float* logits_small = (const float*)d_in[1];
    const float* offs_small   = (const float*)d_in[2];
    const float* pred_large   = (const float*)d_in[3];
    const float* edge_feat    = (const float*)d_in[4];
    const float* cons_feat    = (const float*)d_in[5];
    const float* var_feat     = (const float*)d_in[6];
    const int*   idx_bin      = (const int*)d_in[7];
    const int*   idx_small    = (const int*)d_in[8];
    const int*   idx_large    = (const int*)d_in[9];
    const int*   var_types    = (const int*)d_in[10];
    const int*   edge_indices = (const int*)d_in[11];

    const int NB    = in_sizes[0];
    const int NS    = in_sizes[2];
    const int NL    = in_sizes[3];
    const int E     = in_sizes[4];
    const int NCON  = in_sizes[5] / 8;
    const int NVARS = in_sizes[10];

    const int* rows = edge_indices;
    const int* cols = edge_indices + E;

    // ws layout: x[NVARS] | acc[4] | rep[NREP*NCON]
    float* x   = (float*)d_ws;
    float* acc = x + NVARS;
    float* rep = acc + 4;

    size_t need = (size_t)(NVARS + 4 + (size_t)NREP * NCON) * sizeof(float);
    bool rep_path = (ws_size >= need);

    const int B = 256;

    k_scatter<<<(NB + B - 1) / B, B, 0, stream>>>(prob_bin, idx_bin, x, NB);
    k_small_int<<<(NS + B - 1) / B, B, 0, stream>>>(logits_small, offs_small, idx_small, x, NS);
    k_scatter<<<(NL + B - 1) / B, B, 0, stream>>>(pred_large, idx_large, x, NL);
    k_continuous<<<(NVARS + B - 1) / B, B, 0, stream>>>(var_types, var_feat, x, NVARS);

    int e4 = E / 4;
    if (rep_path) {
        // zero acc + all replicas in one memset
        (void)hipMemsetAsync(acc, 0, (size_t)(4 + (size_t)NREP * NCON) * sizeof(float), stream);
        k_edges_l2<<<4096, B, 0, stream>>>(edge_feat, rows, cols, x, rep, NCON, e4, E);
        k_reduce_rep<NREP><<<1024, B, 0, stream>>>(rep, cons_feat, acc, NCON);
    } else {
        // fallback: single Ax with device-scope atomics
        float* Ax = acc + 4;
        (void)hipMemsetAsync(acc, 0, (size_t)(4 + NCON) * sizeof(float), stream);
        k_edges<<<2048, B, 0, stream>>>(edge_feat, rows, cols, x, Ax, e4, E);
        k_reduce_rep<1><<<1024, B, 0, stream>>>(Ax, cons_feat, acc, NCON);
    }

    k_final<<<1, 64, 0, stream>>>(acc, (float*)d_out, NCON);
}

// Round 5
// 539.591 us; speedup vs baseline: 1.5624x; 1.5624x over previous
//
#include <hip/hip_runtime.h>

// ---------------------------------------------------------------------------
// ConstraintViolationLoss: build x; sparse Ax via deterministic counting-sort
// (per-chunk histogram -> per-bucket chunk scan -> atomic-free scatter) +
// LDS bucket accumulation with plain-store partials; fused violation
// reduction to 4 scalars: [penalty, mean_viol, max_viol, n_violated].
//
// Why: gfx950 fp32 global atomics execute memory-side regardless of scope
// (r1/r4: 16M atomics -> 500MB WRITE_SIZE, ~20.6G atomics/s cap). r2's sort
// lost to 242K contended global cursor atomics + cursor-scattered stores.
// This version has ZERO global atomics on the 16M-edge path.
// ---------------------------------------------------------------------------

#define BSHIFT 13
#define BROWS  (1 << BSHIFT)     // 8192 rows/bucket -> 32KB LDS tile
#define NBUCK_MAX 64
#define CHUNK 16384              // edges per chunk (one block each)
#define SPLIT 8                  // accumulate blocks per bucket

typedef int   iv4 __attribute__((ext_vector_type(4)));
typedef float fv4 __attribute__((ext_vector_type(4)));

// ------------------------------ build x ------------------------------------

__global__ void k_scatter(const float* __restrict__ src, const int* __restrict__ idx,
                          float* __restrict__ x, int n) {
    int i = blockIdx.x * blockDim.x + threadIdx.x;
    if (i < n) x[idx[i]] = src[i];
}

__global__ void k_small_int(const float* __restrict__ logits, const float* __restrict__ offs,
                            const int* __restrict__ idx, float* __restrict__ x, int n) {
    int i = blockIdx.x * blockDim.x + threadIdx.x;
    if (i >= n) return;
    const fv4* lp = reinterpret_cast<const fv4*>(logits + (size_t)i * 16);
    fv4 v0 = lp[0], v1 = lp[1], v2 = lp[2], v3 = lp[3];
    float l[16] = {v0.x, v0.y, v0.z, v0.w, v1.x, v1.y, v1.z, v1.w,
                   v2.x, v2.y, v2.z, v2.w, v3.x, v3.y, v3.z, v3.w};
    float m = l[0];
#pragma unroll
    for (int j = 1; j < 16; ++j) m = fmaxf(m, l[j]);
    float s = 0.f, ws = 0.f;
#pragma unroll
    for (int j = 0; j < 16; ++j) {
        float e = expf(l[j] - m);
        s += e;
        ws += e * (float)j;
    }
    x[idx[i]] = ws / s + offs[i];
}

__global__ void k_continuous(const int* __restrict__ vt, const float* __restrict__ vf,
                             float* __restrict__ x, int n) {
    int v = blockIdx.x * blockDim.x + threadIdx.x;
    if (v < n && vt[v] == 0) x[v] = vf[(size_t)v * 16 + 8];
}

// ------------------- pass A: per-chunk bucket histogram ---------------------

__global__ __launch_bounds__(256) void k_hist2(const int* __restrict__ rows,
                                               int* __restrict__ counts,
                                               int nchunks, int E, int nbuck) {
    __shared__ int h[NBUCK_MAX];
    int tid = threadIdx.x, chunk = blockIdx.x;
    if (tid < NBUCK_MAX) h[tid] = 0;
    __syncthreads();
    int e4max = E >> 2;
    int base4 = chunk * (CHUNK / 4);
#pragma unroll
    for (int k = 0; k < CHUNK / 1024; ++k) {
        int i4 = base4 + k * 256 + tid;
        if (i4 < e4max) {
            iv4 r = reinterpret_cast<const iv4*>(rows)[i4];
            atomicAdd(&h[r.x >> BSHIFT], 1);
            atomicAdd(&h[r.y >> BSHIFT], 1);
            atomicAdd(&h[r.z >> BSHIFT], 1);
            atomicAdd(&h[r.w >> BSHIFT], 1);
        }
    }
    // global scalar tail (E % 4) counted into chunk 0
    if (chunk == 0 && tid < (E & 3))
        atomicAdd(&h[rows[(E & ~3) + tid] >> BSHIFT], 1);
    __syncthreads();
    if (tid < nbuck) counts[(size_t)tid * nchunks + chunk] = h[tid];
}

// ------------- pass B: scan chunks within bucket; bucket bases --------------

__global__ void k_scanchunks(const int* __restrict__ counts, int* __restrict__ off,
                             int* __restrict__ total, int nchunks) {
    int b = blockIdx.x, lane = threadIdx.x;   // 64 threads
    int carry = 0;
    for (int i0 = 0; i0 < nchunks; i0 += 64) {
        int i = i0 + lane;
        int v = (i < nchunks) ? counts[(size_t)b * nchunks + i] : 0;
        int orig = v;
#pragma unroll
        for (int o = 1; o < 64; o <<= 1) {
            int t = __shfl_up(v, o, 64);
            if (lane >= o) v += t;
        }
        if (i < nchunks) off[(size_t)b * nchunks + i] = carry + v - orig;
        carry += __shfl(v, 63, 64);
    }
    if (lane == 0) total[b] = carry;
}

__global__ void k_bases(const int* __restrict__ total, int* __restrict__ base, int nbuck) {
    if (blockIdx.x == 0 && threadIdx.x == 0) {
        int s = 0;
        for (int b = 0; b < nbuck; ++b) { base[b] = s; s += total[b]; }
        base[nbuck] = s;
    }
}

// --------- pass C: deterministic scatter (LDS cursors, no global atomics) ---

__global__ __launch_bounds__(256) void k_scatter2(const int* __restrict__ rows,
                                                  const int* __restrict__ cols,
                                                  const float* __restrict__ ef,
                                                  const float* __restrict__ x,
                                                  const int* __restrict__ off,
                                                  const int* __restrict__ base,
                                                  float* __restrict__ vals,
                                                  unsigned short* __restrict__ locs,
                                                  int nchunks, int E, int nbuck) {
    __shared__ int cur[NBUCK_MAX];
    int tid = threadIdx.x, chunk = blockIdx.x;
    if (tid < nbuck) cur[tid] = base[tid] + off[(size_t)tid * nchunks + chunk];
    __syncthreads();
    int e4max = E >> 2;
    int base4 = chunk * (CHUNK / 4);
#pragma unroll
    for (int k = 0; k < CHUNK / 1024; ++k) {
        int i4 = base4 + k * 256 + tid;
        if (i4 < e4max) {
            iv4 r = reinterpret_cast<const iv4*>(rows)[i4];
            iv4 c = reinterpret_cast<const iv4*>(cols)[i4];
            fv4 f = reinterpret_cast<const fv4*>(ef)[i4];
            int s0 = atomicAdd(&cur[r.x >> BSHIFT], 1);
            vals[s0] = f.x * x[c.x]; locs[s0] = (unsigned short)(r.x & (BROWS - 1));
            int s1 = atomicAdd(&cur[r.y >> BSHIFT], 1);
            vals[s1] = f.y * x[c.y]; locs[s1] = (unsigned short)(r.y & (BROWS - 1));
            int s2 = atomicAdd(&cur[r.z >> BSHIFT], 1);
            vals[s2] = f.z * x[c.z]; locs[s2] = (unsigned short)(r.z & (BROWS - 1));
            int s3 = atomicAdd(&cur[r.w >> BSHIFT], 1);
            vals[s3] = f.w * x[c.w]; locs[s3] = (unsigned short)(r.w & (BROWS - 1));
        }
    }
    if (chunk == 0 && tid < (E & 3)) {
        int e = (E & ~3) + tid;
        int r = rows[e];
        int s = atomicAdd(&cur[r >> BSHIFT], 1);
        vals[s] = ef[e] * x[cols[e]];
        locs[s] = (unsigned short)(r & (BROWS - 1));
    }
}

// -------- pass D: LDS bucket accumulate; plain-store 8 partials/bucket ------

__global__ __launch_bounds__(256) void k_accum2(const float* __restrict__ vals,
                                                const unsigned short* __restrict__ locs,
                                                const int* __restrict__ base,
                                                float* __restrict__ partial) {
    __shared__ float tile[BROWS];
    int tid = threadIdx.x;
    int b = blockIdx.x / SPLIT, s = blockIdx.x % SPLIT;
    for (int i = tid; i < BROWS; i += 256) tile[i] = 0.f;
    __syncthreads();
    int lo = base[b], hi = base[b + 1];
    int len = hi - lo, per = (len + SPLIT - 1) / SPLIT;
    int s0 = lo + s * per;
    int s1 = s0 + per; if (s1 > hi) s1 = hi;
    for (int i = s0 + tid; i < s1; i += 256)
        atomicAdd(&tile[locs[i]], vals[i]);       // ds_add_f32 (LDS, no rtn)
    __syncthreads();
    float* out = partial + ((size_t)blockIdx.x << BSHIFT);
    for (int i = tid; i < BROWS; i += 256) out[i] = tile[i];
}

// ---------------- final: fold partials + bias + relu + reduce ---------------

__global__ void k_reduce_part(const float* __restrict__ partial, const float* __restrict__ cf,
                              float* __restrict__ acc, int ncon) {
    float lsum = 0.f, lmax = 0.f;
    unsigned lcnt = 0;
    int stride = gridDim.x * blockDim.x;
    for (int c = blockIdx.x * blockDim.x + threadIdx.x; c < ncon; c += stride) {
        int b = c >> BSHIFT, i = c & (BROWS - 1);
        const float* p = partial + (((size_t)b * SPLIT) << BSHIFT) + i;
        float v = 0.f;
#pragma unroll
        for (int s = 0; s < SPLIT; ++s) v += p[(size_t)s << BSHIFT];
        v -= cf[(size_t)c * 8 + 1];
        v = v > 0.f ? v : 0.f;
        lsum += v;
        lmax = fmaxf(lmax, v);
        lcnt += (v > 1e-6f) ? 1u : 0u;
    }
#pragma unroll
    for (int o = 32; o > 0; o >>= 1) {
        lsum += __shfl_down(lsum, o);
        lmax = fmaxf(lmax, __shfl_down(lmax, o));
        lcnt += __shfl_down(lcnt, o);
    }
    __shared__ float ssum[4];
    __shared__ float smax[4];
    __shared__ unsigned scnt[4];
    int lane = threadIdx.x & 63, wid = threadIdx.x >> 6;
    if (lane == 0) { ssum[wid] = lsum; smax[wid] = lmax; scnt[wid] = lcnt; }
    __syncthreads();
    if (threadIdx.x == 0) {
        float bs = 0.f, bm = 0.f;
        unsigned bc = 0;
        int nw = (blockDim.x + 63) >> 6;
        for (int w = 0; w < nw; ++w) { bs += ssum[w]; bm = fmaxf(bm, smax[w]); bc += scnt[w]; }
        atomicAdd(&acc[0], bs);
        atomicMax(reinterpret_cast<unsigned*>(acc) + 1, __float_as_uint(bm));
        atomicAdd(reinterpret_cast<unsigned*>(acc) + 2, bc);
    }
}

__global__ void k_final(const float* __restrict__ acc, float* __restrict__ out, int ncon) {
    if (blockIdx.x == 0 && threadIdx.x == 0) {
        float sum = acc[0];
        float mx = __uint_as_float(reinterpret_cast<const unsigned*>(acc)[1]);
        unsigned cnt = reinterpret_cast<const unsigned*>(acc)[2];
        float mean = sum / (float)ncon;
        out[0] = mean + 0.1f * mx;
        out[1] = mean;
        out[2] = mx;
        out[3] = (float)cnt;
    }
}

// ------------------- fallback: direct device-scope atomics ------------------

__global__ void k_edges(const float* __restrict__ ef, const int* __restrict__ rows,
                        const int* __restrict__ cols, const float* __restrict__ x,
                        float* __restrict__ Ax, int e4, int E) {
    int stride = gridDim.x * blockDim.x;
    int gid = blockIdx.x * blockDim.x + threadIdx.x;
    for (int i = gid; i < e4; i += stride) {
        fv4 f = reinterpret_cast<const fv4*>(ef)[i];
        iv4 r = reinterpret_cast<const iv4*>(rows)[i];
        iv4 c = reinterpret_cast<const iv4*>(cols)[i];
        atomicAdd(&Ax[r.x], f.x * x[c.x]);
        atomicAdd(&Ax[r.y], f.y * x[c.y]);
        atomicAdd(&Ax[r.z], f.z * x[c.z]);
        atomicAdd(&Ax[r.w], f.w * x[c.w]);
    }
    for (int e = e4 * 4 + gid; e < E; e += stride)
        atomicAdd(&Ax[rows[e]], ef[e] * x[cols[e]]);
}

__global__ void k_reduce_ax(const float* __restrict__ Ax, const float* __restrict__ cf,
                            float* __restrict__ acc, int ncon) {
    float lsum = 0.f, lmax = 0.f;
    unsigned lcnt = 0;
    int stride = gridDim.x * blockDim.x;
    for (int c = blockIdx.x * blockDim.x + threadIdx.x; c < ncon; c += stride) {
        float v = Ax[c] - cf[(size_t)c * 8 + 1];
        v = v > 0.f ? v : 0.f;
        lsum += v;
        lmax = fmaxf(lmax, v);
        lcnt += (v > 1e-6f) ? 1u : 0u;
    }
#pragma unroll
    for (int o = 32; o > 0; o >>= 1) {
        lsum += __shfl_down(lsum, o);
        lmax = fmaxf(lmax, __shfl_down(lmax, o));
        lcnt += __shfl_down(lcnt, o);
    }
    __shared__ float ssum[4];
    __shared__ float smax[4];
    __shared__ unsigned scnt[4];
    int lane = threadIdx.x & 63, wid = threadIdx.x >> 6;
    if (lane == 0) { ssum[wid] = lsum; smax[wid] = lmax; scnt[wid] = lcnt; }
    __syncthreads();
    if (threadIdx.x == 0) {
        float bs = 0.f, bm = 0.f;
        unsigned bc = 0;
        int nw = (blockDim.x + 63) >> 6;
        for (int w = 0; w < nw; ++w) { bs += ssum[w]; bm = fmaxf(bm, smax[w]); bc += scnt[w]; }
        atomicAdd(&acc[0], bs);
        atomicMax(reinterpret_cast<unsigned*>(acc) + 1, __float_as_uint(bm));
        atomicAdd(reinterpret_cast<unsigned*>(acc) + 2, bc);
    }
}

// ------------------------------ launcher -----------------------------------

extern "C" void kernel_launch(void* const* d_in, const int* in_sizes, int n_in,
                              void* d_out, int out_size, void* d_ws, size_t ws_size,
                              hipStream_t stream) {
    const float* prob_bin     = (const float*)d_in[0];
    const float* logits_small = (const float*)d_in[1];
    const float* offs_small   = (const float*)d_in[2];
    const float* pred_large   = (const float*)d_in[3];
    const float* edge_feat    = (const float*)d_in[4];
    const float* cons_feat    = (const float*)d_in[5];
    const float* var_feat     = (const float*)d_in[6];
    const int*   idx_bin      = (const int*)d_in[7];
    const int*   idx_small    = (const int*)d_in[8];
    const int*   idx_large    = (const int*)d_in[9];
    const int*   var_types    = (const int*)d_in[10];
    const int*   edge_indices = (const int*)d_in[11];

    const int NB    = in_sizes[0];
    const int NS    = in_sizes[2];
    const int NL    = in_sizes[3];
    const int E     = in_sizes[4];
    const int NCON  = in_sizes[5] / 8;
    const int NVARS = in_sizes[10];

    const int* rows = edge_indices;
    const int* cols = edge_indices + E;

    const int nbuck   = (NCON + BROWS - 1) >> BSHIFT;
    const int nchunks = (E + CHUNK - 1) / CHUNK;

    // ws layout (256B-aligned regions)
    char* w = (char*)d_ws;
    size_t o = 0;
    auto take = [&](size_t bytes) -> char* {
        char* p = w + o;
        o = (o + bytes + 255) & ~(size_t)255;
        return p;
    };
    float*          x       = (float*)take((size_t)NVARS * 4);
    float*          vals    = (float*)take((size_t)E * 4);
    unsigned short* locs    = (unsigned short*)take((size_t)E * 2);
    float*          partial = (float*)take((size_t)nbuck * SPLIT * BROWS * 4);
    int*            counts  = (int*)take((size_t)nbuck * nchunks * 4);
    int*            off     = (int*)take((size_t)nbuck * nchunks * 4);
    int*            base    = (int*)take((size_t)(nbuck + 1) * 4);
    int*            total   = (int*)take((size_t)nbuck * 4);
    float*          acc     = (float*)take(16);

    bool sorted_path = (o <= ws_size) && (nbuck <= NBUCK_MAX);

    const int B = 256;

    k_scatter<<<(NB + B - 1) / B, B, 0, stream>>>(prob_bin, idx_bin, x, NB);
    k_small_int<<<(NS + B - 1) / B, B, 0, stream>>>(logits_small, offs_small, idx_small, x, NS);
    k_scatter<<<(NL + B - 1) / B, B, 0, stream>>>(pred_large, idx_large, x, NL);
    k_continuous<<<(NVARS + B - 1) / B, B, 0, stream>>>(var_types, var_feat, x, NVARS);

    if (sorted_path) {
        (void)hipMemsetAsync(acc, 0, 16, stream);
        k_hist2<<<nchunks, B, 0, stream>>>(rows, counts, nchunks, E, nbuck);
        k_scanchunks<<<nbuck, 64, 0, stream>>>(counts, off, total, nchunks);
        k_bases<<<1, 64, 0, stream>>>(total, base, nbuck);
        k_scatter2<<<nchunks, B, 0, stream>>>(rows, cols, edge_feat, x, off, base,
                                              vals, locs, nchunks, E, nbuck);
        k_accum2<<<nbuck * SPLIT, B, 0, stream>>>(vals, locs, base, partial);
        k_reduce_part<<<1024, B, 0, stream>>>(partial, cons_feat, acc, NCON);
    } else {
        // fallback: single Ax with device-scope atomics
        float* accf = (float*)((char*)d_ws + (size_t)NVARS * 4);
        float* Ax   = accf + 4;
        (void)hipMemsetAsync(accf, 0, (size_t)(4 + NCON) * sizeof(float), stream);
        k_edges<<<2048, B, 0, stream>>>(edge_feat, rows, cols, x, Ax, E / 4, E);
        k_reduce_ax<<<1024, B, 0, stream>>>(Ax, cons_feat, accf, NCON);
        acc = accf;
    }

    k_final<<<1, 64, 0, stream>>>(acc, (float*)d_out, NCON);
}

// Round 6
// 314.899 us; speedup vs baseline: 2.6772x; 1.7135x over previous
//
#include <hip/hip_runtime.h>

// ---------------------------------------------------------------------------
// ConstraintViolationLoss: build x; sparse Ax via deterministic counting-sort
// with LDS write-combining (per-bucket FIFO buffers flushed as coalesced
// bursts at precomputed cursors -> no global atomics, no sub-line scatter),
// LDS bucket accumulation, fused violation reduction to 4 scalars:
// [penalty, mean_viol, max_viol, n_violated].
//
// History: r1/r4: 16M fp32 global atomics -> 500MB memory-side RMW (scope
// ignored). r2: global cursor atomics + scattered stores -> 1.05GB. r5:
// deterministic scatter but raw stores scatter over 62 frontiers -> 906MB
// (write-allocate + partial-line writeback). This version: stores leave the
// CU only as >=48-record coalesced bursts.
// ---------------------------------------------------------------------------

#define BSHIFT 14
#define BROWS  (1 << BSHIFT)     // 16384 rows/bucket -> 64KB accum tile
#define NBUCK_MAX 32
#define CHUNK 16384              // edges per chunk (one block each)
#define ROUNDS (CHUNK / 1024)    // 256 threads x 4 edges per round
#define BUF 128                  // LDS FIFO depth per bucket
#define THRESH 48                // flush when fill >= THRESH
#define SPLIT 8                  // accumulate blocks per bucket

typedef int   iv4 __attribute__((ext_vector_type(4)));
typedef float fv4 __attribute__((ext_vector_type(4)));

// ------------------------------ build x ------------------------------------

__global__ void k_scatter(const float* __restrict__ src, const int* __restrict__ idx,
                          float* __restrict__ x, int n) {
    int i = blockIdx.x * blockDim.x + threadIdx.x;
    if (i < n) x[idx[i]] = src[i];
}

__global__ void k_small_int(const float* __restrict__ logits, const float* __restrict__ offs,
                            const int* __restrict__ idx, float* __restrict__ x, int n) {
    int i = blockIdx.x * blockDim.x + threadIdx.x;
    if (i >= n) return;
    const fv4* lp = reinterpret_cast<const fv4*>(logits + (size_t)i * 16);
    fv4 v0 = lp[0], v1 = lp[1], v2 = lp[2], v3 = lp[3];
    float l[16] = {v0.x, v0.y, v0.z, v0.w, v1.x, v1.y, v1.z, v1.w,
                   v2.x, v2.y, v2.z, v2.w, v3.x, v3.y, v3.z, v3.w};
    float m = l[0];
#pragma unroll
    for (int j = 1; j < 16; ++j) m = fmaxf(m, l[j]);
    float s = 0.f, ws = 0.f;
#pragma unroll
    for (int j = 0; j < 16; ++j) {
        float e = expf(l[j] - m);
        s += e;
        ws += e * (float)j;
    }
    x[idx[i]] = ws / s + offs[i];
}

__global__ void k_continuous(const int* __restrict__ vt, const float* __restrict__ vf,
                             float* __restrict__ x, int n) {
    int v = blockIdx.x * blockDim.x + threadIdx.x;
    if (v < n && vt[v] == 0) x[v] = vf[(size_t)v * 16 + 8];
}

// ------------------- pass A: per-chunk bucket histogram ---------------------

__global__ __launch_bounds__(256) void k_hist2(const int* __restrict__ rows,
                                               int* __restrict__ counts,
                                               int nchunks, int E, int nbuck) {
    __shared__ int h[NBUCK_MAX];
    int tid = threadIdx.x, chunk = blockIdx.x;
    if (tid < NBUCK_MAX) h[tid] = 0;
    __syncthreads();
    int e4max = E >> 2;
    int base4 = chunk * (CHUNK / 4);
#pragma unroll
    for (int k = 0; k < CHUNK / 1024; ++k) {
        int i4 = base4 + k * 256 + tid;
        if (i4 < e4max) {
            iv4 r = __builtin_nontemporal_load(reinterpret_cast<const iv4*>(rows) + i4);
            atomicAdd(&h[r.x >> BSHIFT], 1);
            atomicAdd(&h[r.y >> BSHIFT], 1);
            atomicAdd(&h[r.z >> BSHIFT], 1);
            atomicAdd(&h[r.w >> BSHIFT], 1);
        }
    }
    if (chunk == 0 && tid < (E & 3))
        atomicAdd(&h[rows[(E & ~3) + tid] >> BSHIFT], 1);
    __syncthreads();
    if (tid < nbuck) counts[(size_t)tid * nchunks + chunk] = h[tid];
}

// ------------- pass B: scan chunks within bucket; bucket bases --------------

__global__ void k_scanchunks(const int* __restrict__ counts, int* __restrict__ off,
                             int* __restrict__ total, int nchunks) {
    int b = blockIdx.x, lane = threadIdx.x;   // 64 threads
    int carry = 0;
    for (int i0 = 0; i0 < nchunks; i0 += 64) {
        int i = i0 + lane;
        int v = (i < nchunks) ? counts[(size_t)b * nchunks + i] : 0;
        int orig = v;
#pragma unroll
        for (int o = 1; o < 64; o <<= 1) {
            int t = __shfl_up(v, o, 64);
            if (lane >= o) v += t;
        }
        if (i < nchunks) off[(size_t)b * nchunks + i] = carry + v - orig;
        carry += __shfl(v, 63, 64);
    }
    if (lane == 0) total[b] = carry;
}

__global__ void k_bases(const int* __restrict__ total, int* __restrict__ base, int nbuck) {
    if (blockIdx.x == 0 && threadIdx.x == 0) {
        int s = 0;
        for (int b = 0; b < nbuck; ++b) { base[b] = s; s += total[b]; }
        base[nbuck] = s;
    }
}

// ----- pass C: scatter with LDS write-combining (coalesced burst flushes) ---

__global__ __launch_bounds__(256) void k_scatter3(const int* __restrict__ rows,
                                                  const int* __restrict__ cols,
                                                  const float* __restrict__ ef,
                                                  const float* __restrict__ x,
                                                  const int* __restrict__ off,
                                                  const int* __restrict__ base,
                                                  float* __restrict__ vals,
                                                  unsigned short* __restrict__ locs,
                                                  int nchunks, int E, int nbuck) {
    __shared__ float          bufv[NBUCK_MAX][BUF];
    __shared__ unsigned short bufl[NBUCK_MAX][BUF];
    __shared__ int fill[NBUCK_MAX];
    __shared__ int done[NBUCK_MAX];
    __shared__ int cbase[NBUCK_MAX];

    int tid = threadIdx.x, chunk = blockIdx.x;
    if (tid < NBUCK_MAX) {
        fill[tid] = 0;
        done[tid] = 0;
        cbase[tid] = (tid < nbuck) ? base[tid] + off[(size_t)tid * nchunks + chunk] : 0;
    }
    __syncthreads();

    int e4max = E >> 2;
    int base4 = chunk * (CHUNK / 4);
    int wid = tid >> 6, lane = tid & 63;

    for (int k = 0; k < ROUNDS; ++k) {
        int i4 = base4 + k * 256 + tid;
        if (i4 < e4max) {
            iv4 r = __builtin_nontemporal_load(reinterpret_cast<const iv4*>(rows) + i4);
            iv4 c = __builtin_nontemporal_load(reinterpret_cast<const iv4*>(cols) + i4);
            fv4 f = __builtin_nontemporal_load(reinterpret_cast<const fv4*>(ef) + i4);
            int   rr[4] = {r.x, r.y, r.z, r.w};
            int   cc[4] = {c.x, c.y, c.z, c.w};
            float ff[4] = {f.x, f.y, f.z, f.w};
#pragma unroll
            for (int j = 0; j < 4; ++j) {
                int b = rr[j] >> BSHIFT;
                float v = ff[j] * x[cc[j]];
                unsigned short lc = (unsigned short)(rr[j] & (BROWS - 1));
                int pos = atomicAdd(&fill[b], 1);
                if (pos < BUF) { bufv[b][pos] = v; bufl[b][pos] = lc; }
                else {           // deterministic spill slot (rare by design)
                    int g = cbase[b] + done[b] + pos;
                    vals[g] = v; locs[g] = lc;
                }
            }
        }
        // scalar tail (E%4), chunk 0, last round, before final flush
        if (k == ROUNDS - 1 && chunk == 0 && tid < (E & 3)) {
            int e = (E & ~3) + tid;
            int rrow = rows[e];
            int b = rrow >> BSHIFT;
            float v = ef[e] * x[cols[e]];
            unsigned short lc = (unsigned short)(rrow & (BROWS - 1));
            int pos = atomicAdd(&fill[b], 1);
            if (pos < BUF) { bufv[b][pos] = v; bufl[b][pos] = lc; }
            else { int g = cbase[b] + done[b] + pos; vals[g] = v; locs[g] = lc; }
        }
        __syncthreads();
        bool last = (k == ROUNDS - 1);
        for (int b = wid; b < nbuck; b += 4) {      // wave w owns buckets w, w+4, ...
            int fl = fill[b];
            if (fl == 0) continue;
            if (fl >= THRESH || last) {
                int n = fl < BUF ? fl : BUF;
                int g = cbase[b] + done[b];
                for (int j = lane; j < n; j += 64) {
                    vals[g + j] = bufv[b][j];
                    locs[g + j] = bufl[b][j];
                }
                if (lane == 0) { done[b] += fl; fill[b] = 0; }
            }
        }
        __syncthreads();
    }
}

// -------- pass D: LDS bucket accumulate; plain-store partials ---------------

__global__ __launch_bounds__(256) void k_accum3(const float* __restrict__ vals,
                                                const unsigned short* __restrict__ locs,
                                                const int* __restrict__ base,
                                                float* __restrict__ partial) {
    __shared__ float tile[BROWS];   // 64KB
    int tid = threadIdx.x;
    int b = blockIdx.x / SPLIT, s = blockIdx.x % SPLIT;
    for (int i = tid; i < BROWS; i += 256) tile[i] = 0.f;
    __syncthreads();
    int lo = base[b], hi = base[b + 1];
    int len = hi - lo, per = (len + SPLIT - 1) / SPLIT;
    int s0 = lo + s * per;
    int s1 = s0 + per; if (s1 > hi) s1 = hi;
    int i = s0 + tid;
    for (; i + 768 < s1; i += 1024) {
        float v0 = vals[i], v1 = vals[i + 256], v2 = vals[i + 512], v3 = vals[i + 768];
        unsigned short l0 = locs[i], l1 = locs[i + 256], l2 = locs[i + 512], l3 = locs[i + 768];
        atomicAdd(&tile[l0], v0);
        atomicAdd(&tile[l1], v1);
        atomicAdd(&tile[l2], v2);
        atomicAdd(&tile[l3], v3);
    }
    for (; i < s1; i += 256)
        atomicAdd(&tile[locs[i]], vals[i]);
    __syncthreads();
    float* out = partial + ((size_t)blockIdx.x << BSHIFT);
    for (int i2 = tid; i2 < BROWS; i2 += 256) out[i2] = tile[i2];
}

// ---------------- final: fold partials + bias + relu + reduce ---------------

__global__ void k_reduce_part(const float* __restrict__ partial, const float* __restrict__ cf,
                              float* __restrict__ acc, int ncon) {
    float lsum = 0.f, lmax = 0.f;
    unsigned lcnt = 0;
    int stride = gridDim.x * blockDim.x;
    for (int c = blockIdx.x * blockDim.x + threadIdx.x; c < ncon; c += stride) {
        int b = c >> BSHIFT, i = c & (BROWS - 1);
        const float* p = partial + (((size_t)b * SPLIT) << BSHIFT) + i;
        float v = 0.f;
#pragma unroll
        for (int s = 0; s < SPLIT; ++s) v += p[(size_t)s << BSHIFT];
        v -= cf[(size_t)c * 8 + 1];
        v = v > 0.f ? v : 0.f;
        lsum += v;
        lmax = fmaxf(lmax, v);
        lcnt += (v > 1e-6f) ? 1u : 0u;
    }
#pragma unroll
    for (int o = 32; o > 0; o >>= 1) {
        lsum += __shfl_down(lsum, o);
        lmax = fmaxf(lmax, __shfl_down(lmax, o));
        lcnt += __shfl_down(lcnt, o);
    }
    __shared__ float ssum[4];
    __shared__ float smax[4];
    __shared__ unsigned scnt[4];
    int lane = threadIdx.x & 63, wid = threadIdx.x >> 6;
    if (lane == 0) { ssum[wid] = lsum; smax[wid] = lmax; scnt[wid] = lcnt; }
    __syncthreads();
    if (threadIdx.x == 0) {
        float bs = 0.f, bm = 0.f;
        unsigned bc = 0;
        int nw = (blockDim.x + 63) >> 6;
        for (int w = 0; w < nw; ++w) { bs += ssum[w]; bm = fmaxf(bm, smax[w]); bc += scnt[w]; }
        atomicAdd(&acc[0], bs);
        atomicMax(reinterpret_cast<unsigned*>(acc) + 1, __float_as_uint(bm));
        atomicAdd(reinterpret_cast<unsigned*>(acc) + 2, bc);
    }
}

__global__ void k_final(const float* __restrict__ acc, float* __restrict__ out, int ncon) {
    if (blockIdx.x == 0 && threadIdx.x == 0) {
        float sum = acc[0];
        float mx = __uint_as_float(reinterpret_cast<const unsigned*>(acc)[1]);
        unsigned cnt = reinterpret_cast<const unsigned*>(acc)[2];
        float mean = sum / (float)ncon;
        out[0] = mean + 0.1f * mx;
        out[1] = mean;
        out[2] = mx;
        out[3] = (float)cnt;
    }
}

// ------------------- fallback: direct device-scope atomics ------------------

__global__ void k_edges(const float* __restrict__ ef, const int* __restrict__ rows,
                        const int* __restrict__ cols, const float* __restrict__ x,
                        float* __restrict__ Ax, int e4, int E) {
    int stride = gridDim.x * blockDim.x;
    int gid = blockIdx.x * blockDim.x + threadIdx.x;
    for (int i = gid; i < e4; i += stride) {
        fv4 f = reinterpret_cast<const fv4*>(ef)[i];
        iv4 r = reinterpret_cast<const iv4*>(rows)[i];
        iv4 c = reinterpret_cast<const iv4*>(cols)[i];
        atomicAdd(&Ax[r.x], f.x * x[c.x]);
        atomicAdd(&Ax[r.y], f.y * x[c.y]);
        atomicAdd(&Ax[r.z], f.z * x[c.z]);
        atomicAdd(&Ax[r.w], f.w * x[c.w]);
    }
    for (int e = e4 * 4 + gid; e < E; e += stride)
        atomicAdd(&Ax[rows[e]], ef[e] * x[cols[e]]);
}

__global__ void k_reduce_ax(const float* __restrict__ Ax, const float* __restrict__ cf,
                            float* __restrict__ acc, int ncon) {
    float lsum = 0.f, lmax = 0.f;
    unsigned lcnt = 0;
    int stride = gridDim.x * blockDim.x;
    for (int c = blockIdx.x * blockDim.x + threadIdx.x; c < ncon; c += stride) {
        float v = Ax[c] - cf[(size_t)c * 8 + 1];
        v = v > 0.f ? v : 0.f;
        lsum += v;
        lmax = fmaxf(lmax, v);
        lcnt += (v > 1e-6f) ? 1u : 0u;
    }
#pragma unroll
    for (int o = 32; o > 0; o >>= 1) {
        lsum += __shfl_down(lsum, o);
        lmax = fmaxf(lmax, __shfl_down(lmax, o));
        lcnt += __shfl_down(lcnt, o);
    }
    __shared__ float ssum[4];
    __shared__ float smax[4];
    __shared__ unsigned scnt[4];
    int lane = threadIdx.x & 63, wid = threadIdx.x >> 6;
    if (lane == 0) { ssum[wid] = lsum; smax[wid] = lmax; scnt[wid] = lcnt; }
    __syncthreads();
    if (threadIdx.x == 0) {
        float bs = 0.f, bm = 0.f;
        unsigned bc = 0;
        int nw = (blockDim.x + 63) >> 6;
        for (int w = 0; w < nw; ++w) { bs += ssum[w]; bm = fmaxf(bm, smax[w]); bc += scnt[w]; }
        atomicAdd(&acc[0], bs);
        atomicMax(reinterpret_cast<unsigned*>(acc) + 1, __float_as_uint(bm));
        atomicAdd(reinterpret_cast<unsigned*>(acc) + 2, bc);
    }
}

// ------------------------------ launcher -----------------------------------

extern "C" void kernel_launch(void* const* d_in, const int* in_sizes, int n_in,
                              void* d_out, int out_size, void* d_ws, size_t ws_size,
                              hipStream_t stream) {
    const float* prob_bin     = (const float*)d_in[0];
    const float* logits_small = (const float*)d_in[1];
    const float* offs_small   = (const float*)d_in[2];
    const float* pred_large   = (const float*)d_in[3];
    const float* edge_feat    = (const float*)d_in[4];
    const float* cons_feat    = (const float*)d_in[5];
    const float* var_feat     = (const float*)d_in[6];
    const int*   idx_bin      = (const int*)d_in[7];
    const int*   idx_small    = (const int*)d_in[8];
    const int*   idx_large    = (const int*)d_in[9];
    const int*   var_types    = (const int*)d_in[10];
    const int*   edge_indices = (const int*)d_in[11];

    const int NB    = in_sizes[0];
    const int NS    = in_sizes[2];
    const int NL    = in_sizes[3];
    const int E     = in_sizes[4];
    const int NCON  = in_sizes[5] / 8;
    const int NVARS = in_sizes[10];

    const int* rows = edge_indices;
    const int* cols = edge_indices + E;

    const int nbuck   = (NCON + BROWS - 1) >> BSHIFT;
    const int nchunks = (E + CHUNK - 1) / CHUNK;

    // ws layout (256B-aligned regions)
    char* w = (char*)d_ws;
    size_t o = 0;
    auto take = [&](size_t bytes) -> char* {
        char* p = w + o;
        o = (o + bytes + 255) & ~(size_t)255;
        return p;
    };
    float*          x       = (float*)take((size_t)NVARS * 4);
    float*          vals    = (float*)take((size_t)E * 4);
    unsigned short* locs    = (unsigned short*)take((size_t)E * 2);
    float*          partial = (float*)take((size_t)nbuck * SPLIT * BROWS * 4);
    int*            counts  = (int*)take((size_t)nbuck * nchunks * 4);
    int*            off     = (int*)take((size_t)nbuck * nchunks * 4);
    int*            base    = (int*)take((size_t)(nbuck + 1) * 4);
    int*            total   = (int*)take((size_t)nbuck * 4);
    float*          acc     = (float*)take(16);

    bool sorted_path = (o <= ws_size) && (nbuck <= NBUCK_MAX);

    const int B = 256;

    k_scatter<<<(NB + B - 1) / B, B, 0, stream>>>(prob_bin, idx_bin, x, NB);
    k_small_int<<<(NS + B - 1) / B, B, 0, stream>>>(logits_small, offs_small, idx_small, x, NS);
    k_scatter<<<(NL + B - 1) / B, B, 0, stream>>>(pred_large, idx_large, x, NL);
    k_continuous<<<(NVARS + B - 1) / B, B, 0, stream>>>(var_types, var_feat, x, NVARS);

    if (sorted_path) {
        (void)hipMemsetAsync(acc, 0, 16, stream);
        k_hist2<<<nchunks, B, 0, stream>>>(rows, counts, nchunks, E, nbuck);
        k_scanchunks<<<nbuck, 64, 0, stream>>>(counts, off, total, nchunks);
        k_bases<<<1, 64, 0, stream>>>(total, base, nbuck);
        k_scatter3<<<nchunks, B, 0, stream>>>(rows, cols, edge_feat, x, off, base,
                                              vals, locs, nchunks, E, nbuck);
        k_accum3<<<nbuck * SPLIT, B, 0, stream>>>(vals, locs, base, partial);
        k_reduce_part<<<1024, B, 0, stream>>>(partial, cons_feat, acc, NCON);
    } else {
        float* accf = (float*)((char*)d_ws + (size_t)NVARS * 4);
        float* Ax   = accf + 4;
        (void)hipMemsetAsync(accf, 0, (size_t)(4 + NCON) * sizeof(float), stream);
        k_edges<<<2048, B, 0, stream>>>(edge_feat, rows, cols, x, Ax, E / 4, E);
        k_reduce_ax<<<1024, B, 0, stream>>>(Ax, cons_feat, accf, NCON);
        acc = accf;
    }

    k_final<<<1, 64, 0, stream>>>(acc, (float*)d_out, NCON);
}

// Round 7
// 313.304 us; speedup vs baseline: 2.6908x; 1.0051x over previous
//
#include <hip/hip_runtime.h>

// ---------------------------------------------------------------------------
// ConstraintViolationLoss: build x; sparse Ax via deterministic counting-sort
// with LDS write-combining; 4-byte packed records (loc14|bf16 val); fused
// launches (6 total); violation reduction to 4 scalars:
// [penalty, mean_viol, max_viol, n_violated].
//
// History: r1/r4: 16M fp32 global atomics -> 500MB memory-side RMW (scope
// ignored on gfx950). r2: global cursor atomics -> 1.05GB. r5: deterministic
// scatter, raw stores over 62 frontiers -> 906MB. r6: LDS write-combining
// works (WRITE 406->108MB), but 6B records, grid-limited occupancy, and 11
// launches leave 315us. r7: 4B records, CHUNK 8192, prefetch, fusion.
// ---------------------------------------------------------------------------

#define BSHIFT 14
#define BROWS  (1 << BSHIFT)     // 16384 rows/bucket
#define NBUCK_MAX 32
#define CHUNK 8192               // edges per chunk (one block each)
#define ROUNDS (CHUNK / 1024)    // 256 threads x 4 edges per round
#define BUF 128                  // LDS FIFO depth per bucket
#define THRESH 48                // flush when fill >= THRESH
#define SPLIT 16                 // accumulate blocks per bucket

typedef int   iv4 __attribute__((ext_vector_type(4)));
typedef float fv4 __attribute__((ext_vector_type(4)));

// pack row-local index (14b) and bf16(val) into one u32. RNE rounding.
__device__ inline unsigned pack_rec(int loc, float v) {
    unsigned f = __float_as_uint(v);
    unsigned b = (f + 0x7FFFu + ((f >> 16) & 1u)) >> 16;
    return ((unsigned)loc << 16) | b;
}

// ---------------- K1: fused build-x (4 partitions) + edge histogram --------

__global__ __launch_bounds__(256) void k_build_hist(
    const float* __restrict__ prob_bin, const int* __restrict__ idx_bin, int NB, int gBin,
    const float* __restrict__ logits, const float* __restrict__ offs,
    const int* __restrict__ idx_small, int NS, int gSml,
    const float* __restrict__ pred, const int* __restrict__ idx_large, int NL, int gLrg,
    const int* __restrict__ vt, const float* __restrict__ vf, int NV, int gCnt,
    const int* __restrict__ rows, int* __restrict__ counts,
    int nchunks, int E, int nbuck,
    float* __restrict__ x, float* __restrict__ acc)
{
    int blk = blockIdx.x, tid = threadIdx.x;
    if (blk == 0 && tid < 4) reinterpret_cast<unsigned*>(acc)[tid] = 0u;

    if (blk < gBin) {                         // binary scatter
        int i = blk * 256 + tid;
        if (i < NB) x[idx_bin[i]] = prob_bin[i];
        return;
    }
    blk -= gBin;
    if (blk < gSml) {                         // small-int softmax expectation
        int i = blk * 256 + tid;
        if (i < NS) {
            const fv4* lp = reinterpret_cast<const fv4*>(logits + (size_t)i * 16);
            fv4 v0 = lp[0], v1 = lp[1], v2 = lp[2], v3 = lp[3];
            float l[16] = {v0.x, v0.y, v0.z, v0.w, v1.x, v1.y, v1.z, v1.w,
                           v2.x, v2.y, v2.z, v2.w, v3.x, v3.y, v3.z, v3.w};
            float m = l[0];
#pragma unroll
            for (int j = 1; j < 16; ++j) m = fmaxf(m, l[j]);
            float s = 0.f, ws = 0.f;
#pragma unroll
            for (int j = 0; j < 16; ++j) {
                float e = expf(l[j] - m);
                s += e;
                ws += e * (float)j;
            }
            x[idx_small[i]] = ws / s + offs[i];
        }
        return;
    }
    blk -= gSml;
    if (blk < gLrg) {                         // large-int scatter
        int i = blk * 256 + tid;
        if (i < NL) x[idx_large[i]] = pred[i];
        return;
    }
    blk -= gLrg;
    if (blk < gCnt) {                         // continuous override
        int v = blk * 256 + tid;
        if (v < NV && vt[v] == 0) x[v] = vf[(size_t)v * 16 + 8];
        return;
    }
    blk -= gCnt;
    // histogram chunk (normal loads: keep rows resident in L3 for K4)
    __shared__ int h[NBUCK_MAX];
    if (tid < NBUCK_MAX) h[tid] = 0;
    __syncthreads();
    int e4max = E >> 2;
    int base4 = blk * (CHUNK / 4);
#pragma unroll
    for (int k = 0; k < ROUNDS; ++k) {
        int i4 = base4 + k * 256 + tid;
        if (i4 < e4max) {
            iv4 r = reinterpret_cast<const iv4*>(rows)[i4];
            atomicAdd(&h[r.x >> BSHIFT], 1);
            atomicAdd(&h[r.y >> BSHIFT], 1);
            atomicAdd(&h[r.z >> BSHIFT], 1);
            atomicAdd(&h[r.w >> BSHIFT], 1);
        }
    }
    if (blk == 0 && tid < (E & 3))
        atomicAdd(&h[rows[(E & ~3) + tid] >> BSHIFT], 1);
    __syncthreads();
    if (tid < nbuck) counts[(size_t)tid * nchunks + blk] = h[tid];
}

// ------------- K2: scan chunks within bucket; K3: bucket bases --------------

__global__ void k_scanchunks(const int* __restrict__ counts, int* __restrict__ off,
                             int* __restrict__ total, int nchunks) {
    int b = blockIdx.x, lane = threadIdx.x;   // 64 threads
    int carry = 0;
    for (int i0 = 0; i0 < nchunks; i0 += 64) {
        int i = i0 + lane;
        int v = (i < nchunks) ? counts[(size_t)b * nchunks + i] : 0;
        int orig = v;
#pragma unroll
        for (int o = 1; o < 64; o <<= 1) {
            int t = __shfl_up(v, o, 64);
            if (lane >= o) v += t;
        }
        if (i < nchunks) off[(size_t)b * nchunks + i] = carry + v - orig;
        carry += __shfl(v, 63, 64);
    }
    if (lane == 0) total[b] = carry;
}

__global__ void k_bases(const int* __restrict__ total, int* __restrict__ base, int nbuck) {
    if (blockIdx.x == 0 && threadIdx.x == 0) {
        int s = 0;
        for (int b = 0; b < nbuck; ++b) { base[b] = s; s += total[b]; }
        base[nbuck] = s;
    }
}

// ---- K4: scatter with LDS write-combining, packed records, prefetch --------

__global__ __launch_bounds__(256) void k_scatter3(const int* __restrict__ rows,
                                                  const int* __restrict__ cols,
                                                  const float* __restrict__ ef,
                                                  const float* __restrict__ x,
                                                  const int* __restrict__ off,
                                                  const int* __restrict__ base,
                                                  unsigned* __restrict__ recs,
                                                  int nchunks, int E, int nbuck) {
    __shared__ unsigned bufr[NBUCK_MAX][BUF];
    __shared__ int fill[NBUCK_MAX];
    __shared__ int done[NBUCK_MAX];
    __shared__ int cbase[NBUCK_MAX];

    int tid = threadIdx.x, chunk = blockIdx.x;
    if (tid < NBUCK_MAX) {
        fill[tid] = 0;
        done[tid] = 0;
        cbase[tid] = (tid < nbuck) ? base[tid] + off[(size_t)tid * nchunks + chunk] : 0;
    }
    __syncthreads();

    int e4max = E >> 2;
    int base4 = chunk * (CHUNK / 4);
    int wid = tid >> 6, lane = tid & 63;

    iv4 r, c; fv4 f;
    bool valid;
    {
        int i4 = base4 + tid;
        valid = i4 < e4max;
        if (valid) {
            r = __builtin_nontemporal_load(reinterpret_cast<const iv4*>(rows) + i4);
            c = __builtin_nontemporal_load(reinterpret_cast<const iv4*>(cols) + i4);
            f = __builtin_nontemporal_load(reinterpret_cast<const fv4*>(ef) + i4);
        }
    }

    for (int k = 0; k < ROUNDS; ++k) {
        iv4 rr = r, cc = c; fv4 ff = f;
        bool val = valid;
        if (k + 1 < ROUNDS) {                 // prefetch next round across barrier
            int i4 = base4 + (k + 1) * 256 + tid;
            valid = i4 < e4max;
            if (valid) {
                r = __builtin_nontemporal_load(reinterpret_cast<const iv4*>(rows) + i4);
                c = __builtin_nontemporal_load(reinterpret_cast<const iv4*>(cols) + i4);
                f = __builtin_nontemporal_load(reinterpret_cast<const fv4*>(ef) + i4);
            }
        }
        if (val) {
            int   ra[4] = {rr.x, rr.y, rr.z, rr.w};
            int   ca[4] = {cc.x, cc.y, cc.z, cc.w};
            float fa[4] = {ff.x, ff.y, ff.z, ff.w};
#pragma unroll
            for (int j = 0; j < 4; ++j) {
                int b = ra[j] >> BSHIFT;
                unsigned rec = pack_rec(ra[j] & (BROWS - 1), fa[j] * x[ca[j]]);
                int pos = atomicAdd(&fill[b], 1);
                if (pos < BUF) bufr[b][pos] = rec;
                else recs[cbase[b] + done[b] + pos] = rec;   // rare deterministic spill
            }
        }
        if (k == ROUNDS - 1 && chunk == 0 && tid < (E & 3)) {
            int e = (E & ~3) + tid;
            int rrow = rows[e];
            int b = rrow >> BSHIFT;
            unsigned rec = pack_rec(rrow & (BROWS - 1), ef[e] * x[cols[e]]);
            int pos = atomicAdd(&fill[b], 1);
            if (pos < BUF) bufr[b][pos] = rec;
            else recs[cbase[b] + done[b] + pos] = rec;
        }
        __syncthreads();
        bool last = (k == ROUNDS - 1);
        for (int b = wid; b < nbuck; b += 4) {
            int fl = fill[b];
            if (fl == 0) continue;
            if (fl >= THRESH || last) {
                int n = fl < BUF ? fl : BUF;
                int g = cbase[b] + done[b];
                for (int j = lane; j < n; j += 64) recs[g + j] = bufr[b][j];
                if (lane == 0) { done[b] += fl; fill[b] = 0; }
            }
        }
        __syncthreads();
    }
}

// -------- K5: LDS bucket accumulate; plain-store partials -------------------

__global__ __launch_bounds__(256) void k_accum(const unsigned* __restrict__ recs,
                                               const int* __restrict__ base,
                                               float* __restrict__ partial) {
    __shared__ float tile[BROWS];   // 64KB
    int tid = threadIdx.x;
    int b = blockIdx.x / SPLIT, s = blockIdx.x % SPLIT;
    for (int i = tid; i < BROWS; i += 256) tile[i] = 0.f;
    __syncthreads();
    int lo = base[b], hi = base[b + 1];
    int len = hi - lo, per = (len + SPLIT - 1) / SPLIT;
    int s0 = lo + s * per;
    int s1 = s0 + per; if (s1 > hi) s1 = hi;
    int i = s0 + tid;
    for (; i + 768 < s1; i += 1024) {
        unsigned r0 = __builtin_nontemporal_load(recs + i);
        unsigned r1 = __builtin_nontemporal_load(recs + i + 256);
        unsigned r2 = __builtin_nontemporal_load(recs + i + 512);
        unsigned r3 = __builtin_nontemporal_load(recs + i + 768);
        atomicAdd(&tile[r0 >> 16], __uint_as_float((r0 & 0xFFFFu) << 16));
        atomicAdd(&tile[r1 >> 16], __uint_as_float((r1 & 0xFFFFu) << 16));
        atomicAdd(&tile[r2 >> 16], __uint_as_float((r2 & 0xFFFFu) << 16));
        atomicAdd(&tile[r3 >> 16], __uint_as_float((r3 & 0xFFFFu) << 16));
    }
    for (; i < s1; i += 256) {
        unsigned rr = recs[i];
        atomicAdd(&tile[rr >> 16], __uint_as_float((rr & 0xFFFFu) << 16));
    }
    __syncthreads();
    float* out = partial + ((size_t)blockIdx.x << BSHIFT);
    for (int j = tid; j < BROWS; j += 256) out[j] = tile[j];
}

// ------- K6: fold partials + bias + relu + reduce + (ticketed) finalize -----

__global__ __launch_bounds__(256) void k_reduce_fin(const float* __restrict__ partial,
                                                    const float* __restrict__ cf,
                                                    float* __restrict__ acc,
                                                    float* __restrict__ out,
                                                    int ncon, int nblocks) {
    float lsum = 0.f, lmax = 0.f;
    unsigned lcnt = 0;
    int stride = gridDim.x * blockDim.x;
    for (int c = blockIdx.x * blockDim.x + threadIdx.x; c < ncon; c += stride) {
        int b = c >> BSHIFT, i = c & (BROWS - 1);
        const float* p = partial + (((size_t)b * SPLIT) << BSHIFT) + i;
        float v = 0.f;
#pragma unroll
        for (int s = 0; s < SPLIT; ++s)
            v += __builtin_nontemporal_load(p + ((size_t)s << BSHIFT));
        v -= cf[(size_t)c * 8 + 1];
        v = v > 0.f ? v : 0.f;
        lsum += v;
        lmax = fmaxf(lmax, v);
        lcnt += (v > 1e-6f) ? 1u : 0u;
    }
#pragma unroll
    for (int o = 32; o > 0; o >>= 1) {
        lsum += __shfl_down(lsum, o);
        lmax = fmaxf(lmax, __shfl_down(lmax, o));
        lcnt += __shfl_down(lcnt, o);
    }
    __shared__ float ssum[4];
    __shared__ float smax[4];
    __shared__ unsigned scnt[4];
    int lane = threadIdx.x & 63, wid = threadIdx.x >> 6;
    if (lane == 0) { ssum[wid] = lsum; smax[wid] = lmax; scnt[wid] = lcnt; }
    __syncthreads();
    if (threadIdx.x == 0) {
        float bs = 0.f, bm = 0.f;
        unsigned bc = 0;
        int nw = (blockDim.x + 63) >> 6;
        for (int w = 0; w < nw; ++w) { bs += ssum[w]; bm = fmaxf(bm, smax[w]); bc += scnt[w]; }
        atomicAdd(&acc[0], bs);
        atomicMax(reinterpret_cast<unsigned*>(acc) + 1, __float_as_uint(bm));
        atomicAdd(reinterpret_cast<unsigned*>(acc) + 2, bc);
        __threadfence();
        unsigned t = atomicAdd(reinterpret_cast<unsigned*>(acc) + 3, 1u);
        if (t == (unsigned)(nblocks - 1)) {       // last block finalizes
            float sum   = atomicAdd(&acc[0], 0.f);
            unsigned mb = atomicMax(reinterpret_cast<unsigned*>(acc) + 1, 0u);
            unsigned ct = atomicAdd(reinterpret_cast<unsigned*>(acc) + 2, 0u);
            float mean = sum / (float)ncon;
            float mx = __uint_as_float(mb);
            out[0] = mean + 0.1f * mx;
            out[1] = mean;
            out[2] = mx;
            out[3] = (float)ct;
        }
    }
}

// ------------------- fallback: direct device-scope atomics ------------------

__global__ void k_scatter_f(const float* __restrict__ src, const int* __restrict__ idx,
                            float* __restrict__ x, int n) {
    int i = blockIdx.x * blockDim.x + threadIdx.x;
    if (i < n) x[idx[i]] = src[i];
}

__global__ void k_edges(const float* __restrict__ ef, const int* __restrict__ rows,
                        const int* __restrict__ cols, const float* __restrict__ x,
                        float* __restrict__ Ax, int e4, int E) {
    int stride = gridDim.x * blockDim.x;
    int gid = blockIdx.x * blockDim.x + threadIdx.x;
    for (int i = gid; i < e4; i += stride) {
        fv4 f = reinterpret_cast<const fv4*>(ef)[i];
        iv4 r = reinterpret_cast<const iv4*>(rows)[i];
        iv4 c = reinterpret_cast<const iv4*>(cols)[i];
        atomicAdd(&Ax[r.x], f.x * x[c.x]);
        atomicAdd(&Ax[r.y], f.y * x[c.y]);
        atomicAdd(&Ax[r.z], f.z * x[c.z]);
        atomicAdd(&Ax[r.w], f.w * x[c.w]);
    }
    for (int e = e4 * 4 + gid; e < E; e += stride)
        atomicAdd(&Ax[rows[e]], ef[e] * x[cols[e]]);
}

__global__ void k_reduce_ax(const float* __restrict__ Ax, const float* __restrict__ cf,
                            float* __restrict__ acc, int ncon) {
    float lsum = 0.f, lmax = 0.f;
    unsigned lcnt = 0;
    int stride = gridDim.x * blockDim.x;
    for (int c = blockIdx.x * blockDim.x + threadIdx.x; c < ncon; c += stride) {
        float v = Ax[c] - cf[(size_t)c * 8 + 1];
        v = v > 0.f ? v : 0.f;
        lsum += v;
        lmax = fmaxf(lmax, v);
        lcnt += (v > 1e-6f) ? 1u : 0u;
    }
#pragma unroll
    for (int o = 32; o > 0; o >>= 1) {
        lsum += __shfl_down(lsum, o);
        lmax = fmaxf(lmax, __shfl_down(lmax, o));
        lcnt += __shfl_down(lcnt, o);
    }
    __shared__ float ssum[4];
    __shared__ float smax[4];
    __shared__ unsigned scnt[4];
    int lane = threadIdx.x & 63, wid = threadIdx.x >> 6;
    if (lane == 0) { ssum[wid] = lsum; smax[wid] = lmax; scnt[wid] = lcnt; }
    __syncthreads();
    if (threadIdx.x == 0) {
        float bs = 0.f, bm = 0.f;
        unsigned bc = 0;
        int nw = (blockDim.x + 63) >> 6;
        for (int w = 0; w < nw; ++w) { bs += ssum[w]; bm = fmaxf(bm, smax[w]); bc += scnt[w]; }
        atomicAdd(&acc[0], bs);
        atomicMax(reinterpret_cast<unsigned*>(acc) + 1, __float_as_uint(bm));
        atomicAdd(reinterpret_cast<unsigned*>(acc) + 2, bc);
    }
}

__global__ void k_final(const float* __restrict__ acc, float* __restrict__ out, int ncon) {
    if (blockIdx.x == 0 && threadIdx.x == 0) {
        float sum = acc[0];
        float mx = __uint_as_float(reinterpret_cast<const unsigned*>(acc)[1]);
        unsigned cnt = reinterpret_cast<const unsigned*>(acc)[2];
        float mean = sum / (float)ncon;
        out[0] = mean + 0.1f * mx;
        out[1] = mean;
        out[2] = mx;
        out[3] = (float)cnt;
    }
}

__global__ void k_small_int_f(const float* __restrict__ logits, const float* __restrict__ offs,
                              const int* __restrict__ idx, float* __restrict__ x, int n) {
    int i = blockIdx.x * blockDim.x + threadIdx.x;
    if (i >= n) return;
    const fv4* lp = reinterpret_cast<const fv4*>(logits + (size_t)i * 16);
    fv4 v0 = lp[0], v1 = lp[1], v2 = lp[2], v3 = lp[3];
    float l[16] = {v0.x, v0.y, v0.z, v0.w, v1.x, v1.y, v1.z, v1.w,
                   v2.x, v2.y, v2.z, v2.w, v3.x, v3.y, v3.z, v3.w};
    float m = l[0];
#pragma unroll
    for (int j = 1; j < 16; ++j) m = fmaxf(m, l[j]);
    float s = 0.f, ws = 0.f;
#pragma unroll
    for (int j = 0; j < 16; ++j) {
        float e = expf(l[j] - m);
        s += e;
        ws += e * (float)j;
    }
    x[idx[i]] = ws / s + offs[i];
}

__global__ void k_continuous_f(const int* __restrict__ vt, const float* __restrict__ vf,
                               float* __restrict__ x, int n) {
    int v = blockIdx.x * blockDim.x + threadIdx.x;
    if (v < n && vt[v] == 0) x[v] = vf[(size_t)v * 16 + 8];
}

// ------------------------------ launcher -----------------------------------

extern "C" void kernel_launch(void* const* d_in, const int* in_sizes, int n_in,
                              void* d_out, int out_size, void* d_ws, size_t ws_size,
                              hipStream_t stream) {
    const float* prob_bin     = (const float*)d_in[0];
    const float* logits_small = (const float*)d_in[1];
    const float* offs_small   = (const float*)d_in[2];
    const float* pred_large   = (const float*)d_in[3];
    const float* edge_feat    = (const float*)d_in[4];
    const float* cons_feat    = (const float*)d_in[5];
    const float* var_feat     = (const float*)d_in[6];
    const int*   idx_bin      = (const int*)d_in[7];
    const int*   idx_small    = (const int*)d_in[8];
    const int*   idx_large    = (const int*)d_in[9];
    const int*   var_types    = (const int*)d_in[10];
    const int*   edge_indices = (const int*)d_in[11];

    const int NB    = in_sizes[0];
    const int NS    = in_sizes[2];
    const int NL    = in_sizes[3];
    const int E     = in_sizes[4];
    const int NCON  = in_sizes[5] / 8;
    const int NVARS = in_sizes[10];

    const int* rows = edge_indices;
    const int* cols = edge_indices + E;

    const int nbuck   = (NCON + BROWS - 1) >> BSHIFT;
    const int nchunks = (E + CHUNK - 1) / CHUNK;

    // ws layout (256B-aligned regions)
    char* w = (char*)d_ws;
    size_t o = 0;
    auto take = [&](size_t bytes) -> char* {
        char* p = w + o;
        o = (o + bytes + 255) & ~(size_t)255;
        return p;
    };
    float*    x       = (float*)take((size_t)NVARS * 4);
    unsigned* recs    = (unsigned*)take((size_t)E * 4);
    float*    partial = (float*)take((size_t)nbuck * SPLIT * BROWS * 4);
    int*      counts  = (int*)take((size_t)nbuck * nchunks * 4);
    int*      off     = (int*)take((size_t)nbuck * nchunks * 4);
    int*      base    = (int*)take((size_t)(nbuck + 1) * 4);
    int*      total   = (int*)take((size_t)nbuck * 4);
    float*    acc     = (float*)take(16);

    bool sorted_path = (o <= ws_size) && (nbuck <= NBUCK_MAX);

    const int B = 256;

    if (sorted_path) {
        const int gBin = (NB + B - 1) / B;
        const int gSml = (NS + B - 1) / B;
        const int gLrg = (NL + B - 1) / B;
        const int gCnt = (NVARS + B - 1) / B;
        const int grid1 = gBin + gSml + gLrg + gCnt + nchunks;

        k_build_hist<<<grid1, B, 0, stream>>>(
            prob_bin, idx_bin, NB, gBin,
            logits_small, offs_small, idx_small, NS, gSml,
            pred_large, idx_large, NL, gLrg,
            var_types, var_feat, NVARS, gCnt,
            rows, counts, nchunks, E, nbuck, x, acc);
        k_scanchunks<<<nbuck, 64, 0, stream>>>(counts, off, total, nchunks);
        k_bases<<<1, 64, 0, stream>>>(total, base, nbuck);
        k_scatter3<<<nchunks, B, 0, stream>>>(rows, cols, edge_feat, x, off, base,
                                              recs, nchunks, E, nbuck);
        k_accum<<<nbuck * SPLIT, B, 0, stream>>>(recs, base, partial);
        const int rblocks = 1024;
        k_reduce_fin<<<rblocks, B, 0, stream>>>(partial, cons_feat, acc, (float*)d_out,
                                                NCON, rblocks);
    } else {
        float* accf = (float*)((char*)d_ws + (size_t)NVARS * 4);
        float* Ax   = accf + 4;
        (void)hipMemsetAsync(accf, 0, (size_t)(4 + NCON) * sizeof(float), stream);
        k_scatter_f<<<(NB + B - 1) / B, B, 0, stream>>>(prob_bin, idx_bin, x, NB);
        k_small_int_f<<<(NS + B - 1) / B, B, 0, stream>>>(logits_small, offs_small, idx_small, x, NS);
        k_scatter_f<<<(NL + B - 1) / B, B, 0, stream>>>(pred_large, idx_large, x, NL);
        k_continuous_f<<<(NVARS + B - 1) / B, B, 0, stream>>>(var_types, var_feat, x, NVARS);
        k_edges<<<2048, B, 0, stream>>>(edge_feat, rows, cols, x, Ax, E / 4, E);
        k_reduce_ax<<<1024, B, 0, stream>>>(Ax, cons_feat, accf, NCON);
        k_final<<<1, 64, 0, stream>>>(accf, (float*)d_out, NCON);
    }
}